// Round 8
// baseline (651.402 us; speedup 1.0000x reference)
//
#include <hip/hip_runtime.h>
#include <math.h>

#define HID 128
#define HEAD 8
#define DK 16
#define FEDGE 10
#define FNODE 36
#define ESCALE 0.08838834764831845f  // 1/sqrt(128)

__global__ void k_zero_i(int* __restrict__ p, int n) {
  int i = blockIdx.x * 256 + threadIdx.x;
  if (i < n) p[i] = 0;
}

__global__ void k_count(const int* __restrict__ ei, int E, int* __restrict__ cnt) {
  int e = blockIdx.x * 256 + threadIdx.x;
  if (e >= E) return;
  atomicAdd(&cnt[ei[E + e]], 1);
}

__global__ __launch_bounds__(1024) void k_scan(const int* __restrict__ cnt, int* __restrict__ off,
                                               int* __restrict__ cur, int* __restrict__ scsr_s,
                                               int n, int total) {
  __shared__ int s[1024];
  int t = threadIdx.x;
  const int C = (n + 1023) / 1024;
  int local[32];
  int base = t * C;
  int sum = 0;
  for (int j = 0; j < C; ++j) {
    int i = base + j;
    int v = (i < n) ? cnt[i] : 0;
    local[j] = sum;
    sum += v;
  }
  s[t] = sum;
  __syncthreads();
  for (int dd = 1; dd < 1024; dd <<= 1) {
    int v = (t >= dd) ? s[t - dd] : 0;
    __syncthreads();
    s[t] += v;
    __syncthreads();
  }
  int excl = (t == 0) ? 0 : s[t - 1];
  for (int j = 0; j < C; ++j) {
    int i = base + j;
    if (i < n) {
      int o = excl + local[j];
      off[i] = o;
      cur[i] = o;
      scsr_s[o + i] = i;  // self-loop slot source = the node itself
    }
  }
  if (t == 0) off[n] = total;
}

// CSR fill with shifted positions: node n's slots = [off[n]+n, off[n+1]+n+1),
// slot off[n]+n is the self-loop; edge e lands at pmap[e] = pos + t + 1.
__global__ void k_fill(const int* __restrict__ ei, int E, int* __restrict__ cur,
                       int* __restrict__ scsr_s, int* __restrict__ pmap) {
  int e = blockIdx.x * 256 + threadIdx.x;
  if (e >= E) return;
  int t = ei[E + e];
  int pos = atomicAdd(&cur[t], 1) + t + 1;
  pmap[e] = pos;
  scsr_s[pos] = ei[e];
}

__global__ __launch_bounds__(64) void k_l2x(const float* __restrict__ x, float* __restrict__ h0,
                                            int N) {
  int n = blockIdx.x, l = threadIdx.x;
  float v = (l < FNODE) ? x[(size_t)n * FNODE + l] : 0.f;
  float sq = v * v;
  for (int o = 32; o > 0; o >>= 1) sq += __shfl_xor(sq, o, 64);
  float scl = 1.f / fmaxf(sqrtf(sq), 1e-12f);
  if (l < FNODE) h0[(size_t)n * FNODE + l] = v * scl;
}

__global__ void k_l2e(const float* __restrict__ eattr, float* __restrict__ ea, int E) {
  int e = blockIdx.x * 256 + threadIdx.x;
  if (e >= E) return;
  float a[FEDGE];
  float s = 0.f;
  for (int i = 0; i < FEDGE; ++i) {
    a[i] = eattr[(size_t)e * FEDGE + i];
    s += a[i] * a[i];
  }
  float scl = 1.f / fmaxf(sqrtf(s), 1e-12f);
  for (int i = 0; i < FEDGE; ++i) ea[(size_t)e * FEDGE + i] = a[i] * scl;
}

// Weight-only precompute per layer: C = We@Wq [10x128], WeWv = We@Wv [10x128],
// Gram = We We^T [10x10], Wksum[fin x 16] (k-head-sum). Grid = FEDGE blocks x 128 threads.
__global__ __launch_bounds__(128) void k_wprep(const float* __restrict__ We,
                                               const float* __restrict__ Wq,
                                               const float* __restrict__ Wk,
                                               const float* __restrict__ Wv, int fin,
                                               float* __restrict__ C, float* __restrict__ WeWv,
                                               float* __restrict__ Gram,
                                               float* __restrict__ Wksum) {
  int t = blockIdx.x, d = threadIdx.x;
  __shared__ float sw[HID];
  if (d < fin) sw[d] = We[t * fin + d];
  __syncthreads();
  float c = 0.f, wv = 0.f;
  for (int i = 0; i < fin; ++i) {
    c += sw[i] * Wq[i * HID + d];
    wv += sw[i] * Wv[i * HID + d];
  }
  C[t * HID + d] = c;
  WeWv[t * HID + d] = wv;
  if (d < FEDGE) {
    float g = 0.f;
    for (int i = 0; i < fin; ++i) g += sw[i] * We[d * fin + i];
    Gram[t * FEDGE + d] = g;
  }
  for (int r = t; r < fin; r += FEDGE) {
    if (d < DK) {
      float s = 0.f;
#pragma unroll
      for (int hh = 0; hh < HEAD; ++hh) s += Wk[r * HID + hh * DK + d];
      Wksum[r * DK + d] = s;
    }
  }
}

// 256 threads, 8 nodes/block (2500 blocks -> full CU residency). Threads 0-127 compute q,
// 128-255 compute v. k-pass split over two lane-group sets (halved serial chain).
__global__ __launch_bounds__(256) void k1_node8(
    const float* __restrict__ h, int fin, const float* __restrict__ Wq,
    const float* __restrict__ Wksum, const float* __restrict__ Wv, const float* __restrict__ C,
    const int* __restrict__ off, float* __restrict__ qx, float* __restrict__ kb,
    float* __restrict__ vxb, float* __restrict__ Mout, float* __restrict__ energy_csr, int N) {
  int d = threadIdx.x;
  int col = d & 127, half = d >> 7;
  int n0 = blockIdx.x * 8;
  int nb = min(8, N - n0);
  __shared__ __align__(16) float sh[8][132];
  __shared__ float skp[2][8][DK];
  __shared__ float sk[8][DK];
#pragma unroll
  for (int rr = 0; rr < 4; ++rr) {
    int r = half * 4 + rr;
    if (col < fin) sh[r][col] = (r < nb) ? h[(size_t)(n0 + r) * fin + col] : 0.f;
  }
  __syncthreads();
  const float* W = half ? Wv : Wq;
  float acc[8];
#pragma unroll
  for (int r = 0; r < 8; ++r) acc[r] = 0.f;
  int nI4 = fin >> 2;
  for (int i4 = 0; i4 < nI4; ++i4) {
    float w4[4];
#pragma unroll
    for (int j = 0; j < 4; ++j) w4[j] = W[(i4 * 4 + j) * HID + col];
#pragma unroll
    for (int r = 0; r < 8; ++r) {
      float4 hv = *(const float4*)&sh[r][i4 * 4];
      acc[r] += hv.x * w4[0] + hv.y * w4[1] + hv.z * w4[2] + hv.w * w4[3];
    }
  }
  float* outp = half ? vxb : qx;
  for (int r = 0; r < nb; ++r) outp[(size_t)(n0 + r) * HID + col] = acc[r];
  // k = h @ Wksum: 16 lane-groups; group g handles node g&7, fin-half g>>3.
  int grp = d >> 4, j16 = d & 15;
  int node = grp & 7, hk = grp >> 3;
  int i0 = hk * (fin >> 1), i1 = hk ? fin : (fin >> 1);
  float kk = 0.f;
  for (int i = i0; i < i1; ++i) kk += sh[node][i] * Wksum[i * DK + j16];
  skp[hk][node][j16] = kk;
  __syncthreads();
  if (hk == 0) {
    float kv = skp[0][node][j16] + skp[1][node][j16];
    sk[node][j16] = kv;
    if (node < nb) kb[(size_t)(n0 + node) * DK + j16] = kv;
  }
  __syncthreads();
  // self-loop energy -> CSR slot off[n]+n (q-half only; acc holds q)
  if (half == 0) {
    int hd = col >> 4;
    for (int r = 0; r < nb; ++r) {
      float part = acc[r] * sk[r][j16];
#pragma unroll
      for (int o = 8; o; o >>= 1) part += __shfl_xor(part, o, 16);
      if (j16 == 0) {
        int n = n0 + r;
        energy_csr[(size_t)(off[n] + n) * HEAD + hd] = part * ESCALE;
      }
    }
  }
  if (d < HEAD * FEDGE) {
    int hh = d / FEDGE, tt = d - hh * FEDGE;
    float crow[16];
    *(float4*)&crow[0] = *(const float4*)&C[tt * HID + hh * DK + 0];
    *(float4*)&crow[4] = *(const float4*)&C[tt * HID + hh * DK + 4];
    *(float4*)&crow[8] = *(const float4*)&C[tt * HID + hh * DK + 8];
    *(float4*)&crow[12] = *(const float4*)&C[tt * HID + hh * DK + 12];
    for (int r = 0; r < nb; ++r) {
      float m = 0.f;
#pragma unroll
      for (int j = 0; j < DK; ++j) m += sk[r][j] * crow[j];
      Mout[(size_t)(n0 + r) * (HEAD * FEDGE) + d] = m;
    }
  }
}

// Source-grouped edge energies: edges of source s are e = s*deg .. s*deg+deg-1.
// 16 lanes per source load the qx row ONCE and reuse it for all deg edges.
__global__ __launch_bounds__(256) void k2_src(const float* __restrict__ ea,
                                              const int* __restrict__ ei, int E, int deg, int N,
                                              const float* __restrict__ Gram,
                                              const float* __restrict__ M,
                                              const float* __restrict__ qx,
                                              const float* __restrict__ kb,
                                              const int* __restrict__ pmap,
                                              float* __restrict__ energy_csr,
                                              float* __restrict__ sea_csr) {
  int d = threadIdx.x;
  int g = d >> 4, j = d & 15;
  int s = blockIdx.x * 16 + g;
  if (s >= N) return;
  float qh[HEAD];
  const float* qrow = qx + (size_t)s * HID;
#pragma unroll
  for (int h = 0; h < HEAD; ++h) qh[h] = qrow[h * DK + j];
  float gr[FEDGE];
#pragma unroll
  for (int u = 0; u < FEDGE; ++u) gr[u] = (j < FEDGE) ? Gram[j * FEDGE + u] : 0.f;
  for (int t = 0; t < deg; ++t) {
    int e = s * deg + t;
    int dstn = ei[E + e];
    float kbj = kb[(size_t)dstn * DK + j];
    float eav = (j < FEDGE) ? ea[(size_t)e * FEDGE + j] : 0.f;
    float qk[HEAD];
#pragma unroll
    for (int h = 0; h < HEAD; ++h) qk[h] = qh[h] * kbj;
#pragma unroll
    for (int o = 8; o; o >>= 1) {
#pragma unroll
      for (int h = 0; h < HEAD; ++h) qk[h] += __shfl_xor(qk[h], o, 16);
    }
    float eat[FEDGE];
#pragma unroll
    for (int u = 0; u < FEDGE; ++u) eat[u] = __shfl(eav, u, 16);
    float gp = 0.f;
    if (j < FEDGE) {
      float a = 0.f;
#pragma unroll
      for (int u = 0; u < FEDGE; ++u) a += gr[u] * eat[u];
      gp = a * eav;
    }
#pragma unroll
    for (int o = 8; o; o >>= 1) gp += __shfl_xor(gp, o, 16);
    float scl = 1.f / fmaxf(sqrtf(gp), 1e-12f);
    int pos = pmap[e];
    if (j < FEDGE) sea_csr[(size_t)pos * FEDGE + j] = scl * eav;
    if (j < HEAD) {
      float qv = qk[0];
#pragma unroll
      for (int h = 1; h < HEAD; ++h)
        if (j == h) qv = qk[h];
      const float* Mr = M + (size_t)dstn * (HEAD * FEDGE) + j * FEDGE;
      float em = 0.f;
#pragma unroll
      for (int u = 0; u < FEDGE; ++u) em += Mr[u] * eat[u];
      energy_csr[(size_t)pos * HEAD + j] = (qv + scl * em) * ESCALE;
    }
  }
}

// Per-dst-node gather: contiguous CSR energy tile. Pass A: max. Pass B: single
// exp pass accumulating unnormalized l, accv, T; divide by l at the end.
__global__ __launch_bounds__(128) void k3_gather(
    const int* __restrict__ off, const int* __restrict__ scsr_s,
    const float* __restrict__ energy_csr, const float* __restrict__ sea_csr,
    const float* __restrict__ vxb, const float* __restrict__ WeWv, float* __restrict__ agg,
    int N) {
  int b = blockIdx.x;
  int n = ((N & 7) == 0) ? ((b & 7) * (N >> 3) + (b >> 3)) : b;
  int d = threadIdx.x;
  int j16 = d & 15, hd = d >> 4;
  __shared__ float sT[HEAD * FEDGE];
  int base = off[n] + n;
  int cnt = off[n + 1] + n + 1 - base;  // deg + 1 (self first)
  const float* enp = energy_csr + (size_t)base * HEAD + hd;
  float m = -1e30f;
  for (int o = 0; o < cnt; ++o) m = fmaxf(m, enp[(size_t)o * HEAD]);
  float l = 0.f, accv = 0.f, T = 0.f;
  bool doT = (j16 < FEDGE);
  const float* seap = sea_csr + (size_t)base * FEDGE + j16;
#pragma unroll 2
  for (int o = 0; o < cnt; ++o) {
    int s = scsr_s[base + o];
    float p = __expf(enp[(size_t)o * HEAD] - m);
    l += p;
    accv += p * vxb[(size_t)s * HID + d];
    if (doT && o > 0) T += p * seap[(size_t)o * FEDGE];
  }
  float inv = 1.f / l;
  if (doT) sT[hd * FEDGE + j16] = T * inv;
  __syncthreads();
  float y = accv * inv;
#pragma unroll
  for (int t = 0; t < FEDGE; ++t) y += sT[hd * FEDGE + t] * WeWv[t * HID + d];
  agg[(size_t)n * HID + d] = y;
}

// Epilogue, 8 nodes/block (2500 blocks): y = agg@Wo + bo; LN; LN; tanh.
__global__ __launch_bounds__(128) void k_post(const float* __restrict__ agg,
                                              const float* __restrict__ Wo,
                                              const float* __restrict__ bo,
                                              const float* __restrict__ gg,
                                              const float* __restrict__ bb,
                                              float* __restrict__ hout, int N) {
  int d = threadIdx.x;
  int n0 = blockIdx.x * 8;
  int nb = min(8, N - n0);
  __shared__ __align__(16) float sa[8][132];
  __shared__ float smean[8], sinv[8];
  for (int r = 0; r < 8; ++r) sa[r][d] = (r < nb) ? agg[(size_t)(n0 + r) * HID + d] : 0.f;
  __syncthreads();
  float bod = bo[d];
  float z[8];
#pragma unroll
  for (int r = 0; r < 8; ++r) z[r] = bod;
  for (int i4 = 0; i4 < HID / 4; ++i4) {
    float wo4[4];
#pragma unroll
    for (int j = 0; j < 4; ++j) wo4[j] = Wo[(i4 * 4 + j) * HID + d];
#pragma unroll
    for (int r = 0; r < 8; ++r) {
      float4 a = *(const float4*)&sa[r][i4 * 4];
      z[r] += a.x * wo4[0] + a.y * wo4[1] + a.z * wo4[2] + a.w * wo4[3];
    }
  }
  float gd = gg[d], bd = bb[d];
  int r16 = d >> 4, t16 = d & 15;
#pragma unroll
  for (int pass = 0; pass < 2; ++pass) {
    __syncthreads();
    for (int r = 0; r < 8; ++r) sa[r][d] = z[r];
    __syncthreads();
    float mp = 0.f;
#pragma unroll
    for (int i = 0; i < 8; ++i) mp += sa[r16][t16 + 16 * i];
#pragma unroll
    for (int w = 8; w; w >>= 1) mp += __shfl_xor(mp, w, 16);
    float mean = mp * (1.f / 128.f);
    float vp = 0.f;
#pragma unroll
    for (int i = 0; i < 8; ++i) {
      float c = sa[r16][t16 + 16 * i] - mean;
      vp += c * c;
    }
#pragma unroll
    for (int w = 8; w; w >>= 1) vp += __shfl_xor(vp, w, 16);
    if (t16 == 0) {
      smean[r16] = mean;
      sinv[r16] = rsqrtf(vp * (1.f / 128.f) + 1e-5f);
    }
    __syncthreads();
#pragma unroll
    for (int r = 0; r < 8; ++r) z[r] = (z[r] - smean[r]) * sinv[r] * gd + bd;
  }
  for (int r = 0; r < nb; ++r) hout[(size_t)(n0 + r) * HID + d] = tanhf(z[r]);
}

__global__ __launch_bounds__(128) void k4_pool(const float* __restrict__ h,
                                               const int* __restrict__ ipos,
                                               const float* __restrict__ gate,
                                               const float* __restrict__ W1,
                                               const float* __restrict__ b1,
                                               const float* __restrict__ W2,
                                               const float* __restrict__ b2,
                                               float* __restrict__ out, int per_g) {
  int g = blockIdx.x, d = threadIdx.x;
  __shared__ int snode[128];
  __shared__ float satt[128], spool[HID], so[64], sv[2];
  if (d < per_g) snode[d] = ipos[g * per_g + d];
  __syncthreads();
  float sc = -1e30f;
  if (d < per_g) {
    float s = 0.f;
    int node = snode[d];
    for (int i = 0; i < HID; ++i) s += h[(size_t)node * HID + i] * gate[i];
    sc = s;
  }
  satt[d] = sc;
  __syncthreads();
  if (d == 0) {
    float m = -1e30f;
    for (int i = 0; i < per_g; ++i) m = fmaxf(m, satt[i]);
    sv[0] = m;
  }
  __syncthreads();
  float m = sv[0];
  float ex = (d < per_g) ? __expf(sc - m) : 0.f;
  satt[d] = ex;
  __syncthreads();
  if (d == 0) {
    float su = 0.f;
    for (int i = 0; i < per_g; ++i) su += satt[i];
    sv[1] = 1.f / su;
  }
  __syncthreads();
  float inv = sv[1];
  float p = 0.f;
  for (int i = 0; i < per_g; ++i) p += satt[i] * h[(size_t)snode[i] * HID + d];
  spool[d] = p * inv;
  __syncthreads();
  if (d < 64) {
    float o = b1[d];
    for (int i = 0; i < HID; ++i) o += spool[i] * W1[i * 64 + d];
    so[d] = tanhf(o);
  }
  __syncthreads();
  if (d == 0) {
    float z = b2[0];
    for (int i = 0; i < 64; ++i) z += so[i] * W2[i];
    out[g] = 1.f / (1.f + __expf(-z));
  }
}

extern "C" void kernel_launch(void* const* d_in, const int* in_sizes, int n_in, void* d_out,
                              int out_size, void* d_ws, size_t ws_size, hipStream_t stream) {
  const float* x = (const float*)d_in[0];
  const float* eattr = (const float*)d_in[1];
  const float* c0_We = (const float*)d_in[2];
  const float* c0_Wq = (const float*)d_in[3];
  const float* c0_Wk = (const float*)d_in[4];
  const float* c0_Wv = (const float*)d_in[5];
  const float* c0_Wo = (const float*)d_in[6];
  const float* c0_bo = (const float*)d_in[7];
  const float* c0_g = (const float*)d_in[8];
  const float* c0_b = (const float*)d_in[9];
  const float* cs_We = (const float*)d_in[10];
  const float* cs_Wq = (const float*)d_in[11];
  const float* cs_Wk = (const float*)d_in[12];
  const float* cs_Wv = (const float*)d_in[13];
  const float* cs_Wo = (const float*)d_in[14];
  const float* cs_bo = (const float*)d_in[15];
  const float* cs_g = (const float*)d_in[16];
  const float* cs_b = (const float*)d_in[17];
  const float* gate = (const float*)d_in[18];
  const float* W1 = (const float*)d_in[19];
  const float* b1 = (const float*)d_in[20];
  const float* W2 = (const float*)d_in[21];
  const float* b2 = (const float*)d_in[22];
  const int* ei = (const int*)d_in[23];
  const int* ipos = (const int*)d_in[25];

  int N = in_sizes[0] / FNODE;   // 20000
  int E = in_sizes[1] / FEDGE;   // 160000
  int G = out_size;              // 100
  int per_g = in_sizes[25] / G;  // 100
  int deg = E / N;               // 8 (src = repeat(arange(N), deg))
  int ET = E + N;

  float* w = (float*)d_ws;
  float* hA = w;        w += (size_t)N * HID;
  float* hB = w;        w += (size_t)N * HID;
  float* ea = w;        w += (size_t)E * FEDGE;
  float* qx = w;        w += (size_t)N * HID;
  float* kb = w;        w += (size_t)N * DK;
  float* vx = w;        w += (size_t)N * HID;
  float* Mbuf = w;      w += (size_t)N * (HEAD * FEDGE);
  float* energy_csr = w; w += (size_t)ET * HEAD;
  float* sea_csr = w;   w += (size_t)ET * FEDGE;
  float* Wksum = w;     w += HID * DK;
  float* Cbuf = w;      w += FEDGE * HID;
  float* WeWv = w;      w += FEDGE * HID;
  float* Gram = w;      w += FEDGE * FEDGE;
  int* cnt = (int*)w;
  int* off = cnt + (N + 1);
  int* cur = off + (N + 1);
  int* scsr_s = cur + N;
  int* pmap = scsr_s + ET;

  k_zero_i<<<(N + 1 + 255) / 256, 256, 0, stream>>>(cnt, N + 1);
  k_count<<<(E + 255) / 256, 256, 0, stream>>>(ei, E, cnt);
  k_scan<<<1, 1024, 0, stream>>>(cnt, off, cur, scsr_s, N, E);
  k_fill<<<(E + 255) / 256, 256, 0, stream>>>(ei, E, cur, scsr_s, pmap);
  k_l2x<<<N, 64, 0, stream>>>(x, hA, N);
  k_l2e<<<(E + 255) / 256, 256, 0, stream>>>(eattr, ea, E);

  const float* Ws[3][8] = {
      {c0_We, c0_Wq, c0_Wk, c0_Wv, c0_Wo, c0_bo, c0_g, c0_b},
      {cs_We, cs_Wq, cs_Wk, cs_Wv, cs_Wo, cs_bo, cs_g, cs_b},
      {cs_We + FEDGE * HID, cs_Wq + HID * HID, cs_Wk + HID * HID, cs_Wv + HID * HID,
       cs_Wo + HID * HID, cs_bo + HID, cs_g + HID, cs_b + HID}};
  int fins[3] = {FNODE, HID, HID};
  float* hin[3] = {hA, hB, hA};
  float* hout[3] = {hB, hA, hB};

  for (int l = 0; l < 3; ++l) {
    int fin = fins[l];
    k_wprep<<<FEDGE, 128, 0, stream>>>(Ws[l][0], Ws[l][1], Ws[l][2], Ws[l][3], fin, Cbuf, WeWv,
                                       Gram, Wksum);
    k1_node8<<<(N + 7) / 8, 256, 0, stream>>>(hin[l], fin, Ws[l][1], Wksum, Ws[l][3], Cbuf, off,
                                              qx, kb, vx, Mbuf, energy_csr, N);
    k2_src<<<(N + 15) / 16, 256, 0, stream>>>(ea, ei, E, deg, N, Gram, Mbuf, qx, kb, pmap,
                                              energy_csr, sea_csr);
    // agg aliases hin[l] (its contents were consumed by k1 already)
    k3_gather<<<N, 128, 0, stream>>>(off, scsr_s, energy_csr, sea_csr, vx, WeWv, hin[l], N);
    k_post<<<(N + 7) / 8, 128, 0, stream>>>(hin[l], Ws[l][4], Ws[l][5], Ws[l][6], Ws[l][7],
                                            hout[l], N);
  }
  k4_pool<<<G, 128, 0, stream>>>(hB, ipos, gate, W1, b1, W2, b2, (float*)d_out, per_g);
}

// Round 9
// 573.112 us; speedup vs baseline: 1.1366x; 1.1366x over previous
//
#include <hip/hip_runtime.h>
#include <math.h>

#define HID 128
#define HEAD 8
#define DK 16
#define FEDGE 10
#define FNODE 36
#define ESCALE 0.08838834764831845f  // 1/sqrt(128)

__global__ void k_zero_i(int* __restrict__ p, int n) {
  int i = blockIdx.x * 256 + threadIdx.x;
  if (i < n) p[i] = 0;
}

__global__ void k_count(const int* __restrict__ ei, int E, int* __restrict__ cnt) {
  int e = blockIdx.x * 256 + threadIdx.x;
  if (e >= E) return;
  atomicAdd(&cnt[ei[E + e]], 1);
}

__global__ __launch_bounds__(1024) void k_scan(const int* __restrict__ cnt, int* __restrict__ off,
                                               int* __restrict__ cur, int* __restrict__ scsr_s,
                                               int n, int total) {
  __shared__ int s[1024];
  int t = threadIdx.x;
  const int C = (n + 1023) / 1024;
  int local[32];
  int base = t * C;
  int sum = 0;
  for (int j = 0; j < C; ++j) {
    int i = base + j;
    int v = (i < n) ? cnt[i] : 0;
    local[j] = sum;
    sum += v;
  }
  s[t] = sum;
  __syncthreads();
  for (int dd = 1; dd < 1024; dd <<= 1) {
    int v = (t >= dd) ? s[t - dd] : 0;
    __syncthreads();
    s[t] += v;
    __syncthreads();
  }
  int excl = (t == 0) ? 0 : s[t - 1];
  for (int j = 0; j < C; ++j) {
    int i = base + j;
    if (i < n) {
      int o = excl + local[j];
      off[i] = o;
      cur[i] = o;
      scsr_s[o + i] = i;  // self-loop slot source = the node itself
    }
  }
  if (t == 0) off[n] = total;
}

// CSR fill with shifted positions: node n's slots = [off[n]+n, off[n+1]+n+1),
// slot off[n]+n is the self-loop; edge e lands at pmap[e] = pos + t + 1.
__global__ void k_fill(const int* __restrict__ ei, int E, int* __restrict__ cur,
                       int* __restrict__ scsr_s, int* __restrict__ pmap) {
  int e = blockIdx.x * 256 + threadIdx.x;
  if (e >= E) return;
  int t = ei[E + e];
  int pos = atomicAdd(&cur[t], 1) + t + 1;
  pmap[e] = pos;
  scsr_s[pos] = ei[e];
}

// Weight-only precompute per layer: C = We@Wq [10x128], WeWv = We@Wv [10x128],
// Gram = We We^T [10x10], Wksum[fin x 16]. Grid = FEDGE blocks x 128 threads.
__global__ __launch_bounds__(128) void k_wprep(const float* __restrict__ We,
                                               const float* __restrict__ Wq,
                                               const float* __restrict__ Wk,
                                               const float* __restrict__ Wv, int fin,
                                               float* __restrict__ C, float* __restrict__ WeWv,
                                               float* __restrict__ Gram,
                                               float* __restrict__ Wksum) {
  int t = blockIdx.x, d = threadIdx.x;
  __shared__ float sw[HID];
  if (d < fin) sw[d] = We[t * fin + d];
  __syncthreads();
  float c = 0.f, wv = 0.f;
  for (int i = 0; i < fin; ++i) {
    c += sw[i] * Wq[i * HID + d];
    wv += sw[i] * Wv[i * HID + d];
  }
  C[t * HID + d] = c;
  WeWv[t * HID + d] = wv;
  if (d < FEDGE) {
    float g = 0.f;
    for (int i = 0; i < fin; ++i) g += sw[i] * We[d * fin + i];
    Gram[t * FEDGE + d] = g;
  }
  for (int r = t; r < fin; r += FEDGE) {
    if (d < DK) {
      float s = 0.f;
#pragma unroll
      for (int hh = 0; hh < HEAD; ++hh) s += Wk[r * HID + hh * DK + d];
      Wksum[r * DK + d] = s;
    }
  }
}

// Per-edge, once per run: l2norm(eattr), then per layer sea[l][pos] = ea/||ea@We_l||.
__global__ void k_l2e_sea(const float* __restrict__ eattr, const int* __restrict__ pmap,
                          const float* __restrict__ Gram3, float* __restrict__ sea3, int E,
                          int ET) {
  int e = blockIdx.x * 256 + threadIdx.x;
  if (e >= E) return;
  float a[FEDGE];
  float ss = 0.f;
  for (int i = 0; i < FEDGE; ++i) {
    a[i] = eattr[(size_t)e * FEDGE + i];
    ss += a[i] * a[i];
  }
  float s0 = 1.f / fmaxf(sqrtf(ss), 1e-12f);
  for (int i = 0; i < FEDGE; ++i) a[i] *= s0;
  int pos = pmap[e];
  for (int l = 0; l < 3; ++l) {
    const float* G = Gram3 + l * FEDGE * FEDGE;
    float gp = 0.f;
#pragma unroll
    for (int j = 0; j < FEDGE; ++j) {
      float t = 0.f;
#pragma unroll
      for (int u = 0; u < FEDGE; ++u) t += G[j * FEDGE + u] * a[u];
      gp += t * a[j];
    }
    float scl = 1.f / fmaxf(sqrtf(gp), 1e-12f);
    float* sp = sea3 + (size_t)l * ET * FEDGE + (size_t)pos * FEDGE;
#pragma unroll
    for (int u = 0; u < FEDGE; ++u) sp[u] = scl * a[u];
  }
}

// Layer-0 k1 with fused l2norm(x). 256 threads, 16 nodes/block.
__global__ __launch_bounds__(256) void k1_l2x(
    const float* __restrict__ x, const float* __restrict__ Wq, const float* __restrict__ Wksum,
    const float* __restrict__ Wv, const float* __restrict__ C, const int* __restrict__ off,
    float* __restrict__ qx, float* __restrict__ kb, float* __restrict__ vxb,
    float* __restrict__ Mout, float* __restrict__ energy_csr, int N) {
  const int fin = FNODE;
  int d = threadIdx.x;
  int col = d & 127, half = d >> 7;
  int n0 = blockIdx.x * 16;
  int nb = min(16, N - n0);
  __shared__ __align__(16) float sh[16][132];
  __shared__ float sk[16][DK];
#pragma unroll
  for (int rr = 0; rr < 8; ++rr) {
    int r = half * 8 + rr;
    if (col < fin) sh[r][col] = (r < nb) ? x[(size_t)(n0 + r) * fin + col] : 0.f;
  }
  __syncthreads();
  int grp = d >> 4, j16 = d & 15;
  {  // l2norm row grp in-place
    float ssq = 0.f;
    for (int i = j16; i < fin; i += 16) ssq += sh[grp][i] * sh[grp][i];
#pragma unroll
    for (int o = 8; o; o >>= 1) ssq += __shfl_xor(ssq, o, 16);
    float scl = 1.f / fmaxf(sqrtf(ssq), 1e-12f);
    for (int i = j16; i < fin; i += 16) sh[grp][i] *= scl;
  }
  __syncthreads();
  const float* W = half ? Wv : Wq;
  float acc[16];
#pragma unroll
  for (int r = 0; r < 16; ++r) acc[r] = 0.f;
  const int nI4 = fin >> 2;  // 9
  for (int i4 = 0; i4 < nI4; ++i4) {
    float w4[4];
#pragma unroll
    for (int j = 0; j < 4; ++j) w4[j] = W[(i4 * 4 + j) * HID + col];
#pragma unroll
    for (int r = 0; r < 16; ++r) {
      float4 hv = *(const float4*)&sh[r][i4 * 4];
      acc[r] += hv.x * w4[0] + hv.y * w4[1] + hv.z * w4[2] + hv.w * w4[3];
    }
  }
  float* outp = half ? vxb : qx;
  for (int r = 0; r < nb; ++r) outp[(size_t)(n0 + r) * HID + col] = acc[r];
  {  // k = h @ Wksum: group grp handles node grp
    float kk = 0.f;
    for (int i = 0; i < fin; ++i) kk += sh[grp][i] * Wksum[i * DK + j16];
    sk[grp][j16] = kk;
    if (grp < nb) kb[(size_t)(n0 + grp) * DK + j16] = kk;
  }
  __syncthreads();
  if (half == 0) {  // self-loop energy (acc holds q)
    int hd = col >> 4;
    for (int r = 0; r < nb; ++r) {
      float part = acc[r] * sk[r][j16];
#pragma unroll
      for (int o = 8; o; o >>= 1) part += __shfl_xor(part, o, 16);
      if (j16 == 0) {
        int n = n0 + r;
        energy_csr[(size_t)(off[n] + n) * HEAD + hd] = part * ESCALE;
      }
    }
  }
  if (d < HEAD * FEDGE) {  // M[n][h][16-padded]
    int hh = d / FEDGE, tt = d - hh * FEDGE;
    float crow[16];
    *(float4*)&crow[0] = *(const float4*)&C[tt * HID + hh * DK + 0];
    *(float4*)&crow[4] = *(const float4*)&C[tt * HID + hh * DK + 4];
    *(float4*)&crow[8] = *(const float4*)&C[tt * HID + hh * DK + 8];
    *(float4*)&crow[12] = *(const float4*)&C[tt * HID + hh * DK + 12];
    for (int r = 0; r < nb; ++r) {
      float m = 0.f;
#pragma unroll
      for (int j = 0; j < DK; ++j) m += sk[r][j] * crow[j];
      Mout[((size_t)(n0 + r) * HEAD + hh) * 16 + tt] = m;
    }
  }
}

// Fused: post(layer l) -> k1(layer l+1), 16 nodes/block, 256 threads, fin=128.
// agg and qx may alias (reads fully staged to LDS before qx writes).
__global__ __launch_bounds__(256) void k_post_k1(
    const float* agg, const float* __restrict__ Wo, const float* __restrict__ bo,
    const float* __restrict__ gg, const float* __restrict__ bb, const float* __restrict__ Wq,
    const float* __restrict__ Wksum, const float* __restrict__ Wv, const float* __restrict__ C,
    const int* __restrict__ off, float* qx, float* __restrict__ kb, float* __restrict__ vxb,
    float* __restrict__ Mout, float* __restrict__ energy_csr, int N) {
  const int fin = HID;
  int d = threadIdx.x;
  int col = d & 127, half = d >> 7;
  int n0 = blockIdx.x * 16;
  int nb = min(16, N - n0);
  __shared__ __align__(16) float sa[16][132];
  __shared__ float sk[16][DK];
  __shared__ float smean[16], sinv[16];
#pragma unroll
  for (int rr = 0; rr < 8; ++rr) {
    int r = half * 8 + rr;
    sa[r][col] = (r < nb) ? agg[(size_t)(n0 + r) * HID + col] : 0.f;
  }
  __syncthreads();
  // ---- post: z = agg@Wo + bo (each half owns 8 rows) ----
  float bod = bo[col];
  float z[8];
#pragma unroll
  for (int rr = 0; rr < 8; ++rr) z[rr] = bod;
  for (int i4 = 0; i4 < HID / 4; ++i4) {
    float wo4[4];
#pragma unroll
    for (int j = 0; j < 4; ++j) wo4[j] = Wo[(i4 * 4 + j) * HID + col];
#pragma unroll
    for (int rr = 0; rr < 8; ++rr) {
      float4 a4 = *(const float4*)&sa[half * 8 + rr][i4 * 4];
      z[rr] += a4.x * wo4[0] + a4.y * wo4[1] + a4.z * wo4[2] + a4.w * wo4[3];
    }
  }
  float gd = gg[col], bd = bb[col];
  int grp = d >> 4, j16 = d & 15;
#pragma unroll
  for (int pass = 0; pass < 2; ++pass) {  // LayerNorm applied twice
    __syncthreads();
#pragma unroll
    for (int rr = 0; rr < 8; ++rr) sa[half * 8 + rr][col] = z[rr];
    __syncthreads();
    float mp = 0.f;
#pragma unroll
    for (int i = 0; i < 8; ++i) mp += sa[grp][j16 + 16 * i];
#pragma unroll
    for (int w = 8; w; w >>= 1) mp += __shfl_xor(mp, w, 16);
    float mean = mp * (1.f / 128.f);
    float vp = 0.f;
#pragma unroll
    for (int i = 0; i < 8; ++i) {
      float c = sa[grp][j16 + 16 * i] - mean;
      vp += c * c;
    }
#pragma unroll
    for (int w = 8; w; w >>= 1) vp += __shfl_xor(vp, w, 16);
    if (j16 == 0) {
      smean[grp] = mean;
      sinv[grp] = rsqrtf(vp * (1.f / 128.f) + 1e-5f);
    }
    __syncthreads();
#pragma unroll
    for (int rr = 0; rr < 8; ++rr) {
      int r = half * 8 + rr;
      z[rr] = (z[rr] - smean[r]) * sinv[r] * gd + bd;
    }
  }
  __syncthreads();
#pragma unroll
  for (int rr = 0; rr < 8; ++rr) sa[half * 8 + rr][col] = tanhf(z[rr]);
  __syncthreads();
  // ---- k1 on the LDS h-tile ----
  const float* W = half ? Wv : Wq;
  float acc[16];
#pragma unroll
  for (int r = 0; r < 16; ++r) acc[r] = 0.f;
  for (int i4 = 0; i4 < fin / 4; ++i4) {
    float w4[4];
#pragma unroll
    for (int j = 0; j < 4; ++j) w4[j] = W[(i4 * 4 + j) * HID + col];
#pragma unroll
    for (int r = 0; r < 16; ++r) {
      float4 hv = *(const float4*)&sa[r][i4 * 4];
      acc[r] += hv.x * w4[0] + hv.y * w4[1] + hv.z * w4[2] + hv.w * w4[3];
    }
  }
  float* outp = half ? vxb : qx;
  for (int r = 0; r < nb; ++r) outp[(size_t)(n0 + r) * HID + col] = acc[r];
  {
    float kk = 0.f;
    for (int i = 0; i < fin; ++i) kk += sa[grp][i] * Wksum[i * DK + j16];
    sk[grp][j16] = kk;
    if (grp < nb) kb[(size_t)(n0 + grp) * DK + j16] = kk;
  }
  __syncthreads();
  if (half == 0) {
    int hd = col >> 4;
    for (int r = 0; r < nb; ++r) {
      float part = acc[r] * sk[r][j16];
#pragma unroll
      for (int o = 8; o; o >>= 1) part += __shfl_xor(part, o, 16);
      if (j16 == 0) {
        int n = n0 + r;
        energy_csr[(size_t)(off[n] + n) * HEAD + hd] = part * ESCALE;
      }
    }
  }
  if (d < HEAD * FEDGE) {
    int hh = d / FEDGE, tt = d - hh * FEDGE;
    float crow[16];
    *(float4*)&crow[0] = *(const float4*)&C[tt * HID + hh * DK + 0];
    *(float4*)&crow[4] = *(const float4*)&C[tt * HID + hh * DK + 4];
    *(float4*)&crow[8] = *(const float4*)&C[tt * HID + hh * DK + 8];
    *(float4*)&crow[12] = *(const float4*)&C[tt * HID + hh * DK + 12];
    for (int r = 0; r < nb; ++r) {
      float m = 0.f;
#pragma unroll
      for (int j = 0; j < DK; ++j) m += sk[r][j] * crow[j];
      Mout[((size_t)(n0 + r) * HEAD + hh) * 16 + tt] = m;
    }
  }
}

// Per-(edge,head) energies: no cross-lane ops. 256 threads = 32 edges.
__global__ __launch_bounds__(256) void k2_eh(const int* __restrict__ ei, int E,
                                             const float* __restrict__ qx,
                                             const float* __restrict__ kb,
                                             const float* __restrict__ Mbuf,
                                             const float* __restrict__ sea,
                                             const int* __restrict__ pmap,
                                             float* __restrict__ energy_csr) {
  int gid = blockIdx.x * 256 + threadIdx.x;
  if (gid >= E * HEAD) return;
  int e = gid >> 3, h = gid & 7;
  int s = ei[e], t = ei[E + e];
  int pos = pmap[e];
  const float4* qp = (const float4*)(qx + (size_t)s * HID + h * DK);
  const float4* kp = (const float4*)(kb + (size_t)t * DK);
  float en = 0.f;
#pragma unroll
  for (int j = 0; j < 4; ++j) {
    float4 q4 = qp[j], k4 = kp[j];
    en += q4.x * k4.x + q4.y * k4.y + q4.z * k4.z + q4.w * k4.w;
  }
  const float* Mp = Mbuf + ((size_t)t * HEAD + h) * 16;
  const float* sp = sea + (size_t)pos * FEDGE;
#pragma unroll
  for (int u = 0; u < FEDGE; ++u) en += Mp[u] * sp[u];
  energy_csr[(size_t)pos * HEAD + h] = en * ESCALE;
}

// Per-dst-node gather: contiguous CSR energy tile; single exp pass. agg may alias qx.
__global__ __launch_bounds__(128) void k3_gather(
    const int* __restrict__ off, const int* __restrict__ scsr_s,
    const float* __restrict__ energy_csr, const float* __restrict__ sea,
    const float* __restrict__ vxb, const float* __restrict__ WeWv, float* agg, int N) {
  int b = blockIdx.x;
  int n = ((N & 7) == 0) ? ((b & 7) * (N >> 3) + (b >> 3)) : b;
  int d = threadIdx.x;
  int j16 = d & 15, hd = d >> 4;
  __shared__ float sT[HEAD * FEDGE];
  int base = off[n] + n;
  int cnt = off[n + 1] + n + 1 - base;  // deg + 1 (self first)
  const float* enp = energy_csr + (size_t)base * HEAD + hd;
  float m = -1e30f;
  for (int o = 0; o < cnt; ++o) m = fmaxf(m, enp[(size_t)o * HEAD]);
  float l = 0.f, accv = 0.f, T = 0.f;
  bool doT = (j16 < FEDGE);
  const float* seap = sea + (size_t)base * FEDGE + j16;
#pragma unroll 2
  for (int o = 0; o < cnt; ++o) {
    int s = scsr_s[base + o];
    float p = __expf(enp[(size_t)o * HEAD] - m);
    l += p;
    accv += p * vxb[(size_t)s * HID + d];
    if (doT && o > 0) T += p * seap[(size_t)o * FEDGE];
  }
  float inv = 1.f / l;
  if (doT) sT[hd * FEDGE + j16] = T * inv;
  __syncthreads();
  float y = accv * inv;
#pragma unroll
  for (int t = 0; t < FEDGE; ++t) y += sT[hd * FEDGE + t] * WeWv[t * HID + d];
  agg[(size_t)n * HID + d] = y;
}

// Final epilogue, 16 nodes/block: y = agg@Wo + bo; LN; LN; tanh -> hout.
__global__ __launch_bounds__(128) void k_post(const float* agg, const float* __restrict__ Wo,
                                              const float* __restrict__ bo,
                                              const float* __restrict__ gg,
                                              const float* __restrict__ bb,
                                              float* __restrict__ hout, int N) {
  int d = threadIdx.x;
  int n0 = blockIdx.x * 16;
  int nb = min(16, N - n0);
  __shared__ __align__(16) float sa[16][132];
  __shared__ float smean[16], sinv[16];
  for (int r = 0; r < 16; ++r) sa[r][d] = (r < nb) ? agg[(size_t)(n0 + r) * HID + d] : 0.f;
  __syncthreads();
  float bod = bo[d];
  float z[16];
#pragma unroll
  for (int r = 0; r < 16; ++r) z[r] = bod;
  for (int i4 = 0; i4 < HID / 4; ++i4) {
    float wo4[4];
#pragma unroll
    for (int j = 0; j < 4; ++j) wo4[j] = Wo[(i4 * 4 + j) * HID + d];
#pragma unroll
    for (int r = 0; r < 16; ++r) {
      float4 a = *(const float4*)&sa[r][i4 * 4];
      z[r] += a.x * wo4[0] + a.y * wo4[1] + a.z * wo4[2] + a.w * wo4[3];
    }
  }
  float gd = gg[d], bd = bb[d];
  int r8 = d >> 3, t8 = d & 7;
#pragma unroll
  for (int pass = 0; pass < 2; ++pass) {
    __syncthreads();
    for (int r = 0; r < 16; ++r) sa[r][d] = z[r];
    __syncthreads();
    float mp = 0.f;
#pragma unroll
    for (int i = 0; i < 16; ++i) mp += sa[r8][t8 + 8 * i];
#pragma unroll
    for (int w = 4; w; w >>= 1) mp += __shfl_xor(mp, w, 8);
    float mean = mp * (1.f / 128.f);
    float vp = 0.f;
#pragma unroll
    for (int i = 0; i < 16; ++i) {
      float c = sa[r8][t8 + 8 * i] - mean;
      vp += c * c;
    }
#pragma unroll
    for (int w = 4; w; w >>= 1) vp += __shfl_xor(vp, w, 8);
    if (t8 == 0) {
      smean[r8] = mean;
      sinv[r8] = rsqrtf(vp * (1.f / 128.f) + 1e-5f);
    }
    __syncthreads();
#pragma unroll
    for (int r = 0; r < 16; ++r) z[r] = (z[r] - smean[r]) * sinv[r] * gd + bd;
  }
  for (int r = 0; r < nb; ++r) hout[(size_t)(n0 + r) * HID + d] = tanhf(z[r]);
}

__global__ __launch_bounds__(128) void k4_pool(const float* __restrict__ h,
                                               const int* __restrict__ ipos,
                                               const float* __restrict__ gate,
                                               const float* __restrict__ W1,
                                               const float* __restrict__ b1,
                                               const float* __restrict__ W2,
                                               const float* __restrict__ b2,
                                               float* __restrict__ out, int per_g) {
  int g = blockIdx.x, d = threadIdx.x;
  __shared__ int snode[128];
  __shared__ float satt[128], spool[HID], so[64], sv[2];
  if (d < per_g) snode[d] = ipos[g * per_g + d];
  __syncthreads();
  float sc = -1e30f;
  if (d < per_g) {
    float s = 0.f;
    int node = snode[d];
    for (int i = 0; i < HID; ++i) s += h[(size_t)node * HID + i] * gate[i];
    sc = s;
  }
  satt[d] = sc;
  __syncthreads();
  if (d == 0) {
    float m = -1e30f;
    for (int i = 0; i < per_g; ++i) m = fmaxf(m, satt[i]);
    sv[0] = m;
  }
  __syncthreads();
  float m = sv[0];
  float ex = (d < per_g) ? __expf(sc - m) : 0.f;
  satt[d] = ex;
  __syncthreads();
  if (d == 0) {
    float su = 0.f;
    for (int i = 0; i < per_g; ++i) su += satt[i];
    sv[1] = 1.f / su;
  }
  __syncthreads();
  float inv = sv[1];
  float p = 0.f;
  for (int i = 0; i < per_g; ++i) p += satt[i] * h[(size_t)snode[i] * HID + d];
  spool[d] = p * inv;
  __syncthreads();
  if (d < 64) {
    float o = b1[d];
    for (int i = 0; i < HID; ++i) o += spool[i] * W1[i * 64 + d];
    so[d] = tanhf(o);
  }
  __syncthreads();
  if (d == 0) {
    float z = b2[0];
    for (int i = 0; i < 64; ++i) z += so[i] * W2[i];
    out[g] = 1.f / (1.f + __expf(-z));
  }
}

extern "C" void kernel_launch(void* const* d_in, const int* in_sizes, int n_in, void* d_out,
                              int out_size, void* d_ws, size_t ws_size, hipStream_t stream) {
  const float* x = (const float*)d_in[0];
  const float* eattr = (const float*)d_in[1];
  const float* c0_We = (const float*)d_in[2];
  const float* c0_Wq = (const float*)d_in[3];
  const float* c0_Wk = (const float*)d_in[4];
  const float* c0_Wv = (const float*)d_in[5];
  const float* c0_Wo = (const float*)d_in[6];
  const float* c0_bo = (const float*)d_in[7];
  const float* c0_g = (const float*)d_in[8];
  const float* c0_b = (const float*)d_in[9];
  const float* cs_We = (const float*)d_in[10];
  const float* cs_Wq = (const float*)d_in[11];
  const float* cs_Wk = (const float*)d_in[12];
  const float* cs_Wv = (const float*)d_in[13];
  const float* cs_Wo = (const float*)d_in[14];
  const float* cs_bo = (const float*)d_in[15];
  const float* cs_g = (const float*)d_in[16];
  const float* cs_b = (const float*)d_in[17];
  const float* gate = (const float*)d_in[18];
  const float* W1 = (const float*)d_in[19];
  const float* b1 = (const float*)d_in[20];
  const float* W2 = (const float*)d_in[21];
  const float* b2 = (const float*)d_in[22];
  const int* ei = (const int*)d_in[23];
  const int* ipos = (const int*)d_in[25];

  int N = in_sizes[0] / FNODE;   // 20000
  int E = in_sizes[1] / FEDGE;   // 160000
  int G = out_size;              // 100
  int per_g = in_sizes[25] / G;  // 100
  int ET = E + N;

  float* w = (float*)d_ws;
  float* hB = w;         w += (size_t)N * HID;
  float* qx = w;         w += (size_t)N * HID;  // doubles as agg
  float* kb = w;         w += (size_t)N * DK;
  float* vx = w;         w += (size_t)N * HID;
  float* Mbuf = w;       w += (size_t)N * HEAD * 16;
  float* energy_csr = w; w += (size_t)ET * HEAD;
  float* sea3 = w;       w += (size_t)3 * ET * FEDGE;
  float* C3 = w;         w += 3 * FEDGE * HID;
  float* WeWv3 = w;      w += 3 * FEDGE * HID;
  float* Gram3 = w;      w += 3 * FEDGE * FEDGE;
  float* Wksum3 = w;     w += 3 * HID * DK;
  int* cnt = (int*)w;
  int* off = cnt + (N + 1);
  int* cur = off + (N + 1);
  int* scsr_s = cur + N;
  int* pmap = scsr_s + ET;

  const float* Ws[3][8] = {
      {c0_We, c0_Wq, c0_Wk, c0_Wv, c0_Wo, c0_bo, c0_g, c0_b},
      {cs_We, cs_Wq, cs_Wk, cs_Wv, cs_Wo, cs_bo, cs_g, cs_b},
      {cs_We + FEDGE * HID, cs_Wq + HID * HID, cs_Wk + HID * HID, cs_Wv + HID * HID,
       cs_Wo + HID * HID, cs_bo + HID, cs_g + HID, cs_b + HID}};
  int fins[3] = {FNODE, HID, HID};

  for (int l = 0; l < 3; ++l)
    k_wprep<<<FEDGE, 128, 0, stream>>>(Ws[l][0], Ws[l][1], Ws[l][2], Ws[l][3], fins[l],
                                       C3 + l * FEDGE * HID, WeWv3 + l * FEDGE * HID,
                                       Gram3 + l * FEDGE * FEDGE, Wksum3 + l * HID * DK);
  k_zero_i<<<(N + 1 + 255) / 256, 256, 0, stream>>>(cnt, N + 1);
  k_count<<<(E + 255) / 256, 256, 0, stream>>>(ei, E, cnt);
  k_scan<<<1, 1024, 0, stream>>>(cnt, off, cur, scsr_s, N, E);
  k_fill<<<(E + 255) / 256, 256, 0, stream>>>(ei, E, cur, scsr_s, pmap);
  k_l2e_sea<<<(E + 255) / 256, 256, 0, stream>>>(eattr, pmap, Gram3, sea3, E, ET);

  k1_l2x<<<(N + 15) / 16, 256, 0, stream>>>(x, Ws[0][1], Wksum3, Ws[0][3], C3, off, qx, kb, vx,
                                            Mbuf, energy_csr, N);
  for (int l = 0; l < 3; ++l) {
    const float* sea_l = sea3 + (size_t)l * ET * FEDGE;
    k2_eh<<<(E * HEAD + 255) / 256, 256, 0, stream>>>(ei, E, qx, kb, Mbuf, sea_l, pmap,
                                                      energy_csr);
    k3_gather<<<N, 128, 0, stream>>>(off, scsr_s, energy_csr, sea_l, vx,
                                     WeWv3 + l * FEDGE * HID, qx /*agg*/, N);
    if (l < 2) {
      k_post_k1<<<(N + 15) / 16, 256, 0, stream>>>(
          qx /*agg*/, Ws[l][4], Ws[l][5], Ws[l][6], Ws[l][7], Ws[l + 1][1],
          Wksum3 + (l + 1) * HID * DK, Ws[l + 1][3], C3 + (l + 1) * FEDGE * HID, off, qx, kb, vx,
          Mbuf, energy_csr, N);
    } else {
      k_post<<<(N + 15) / 16, 128, 0, stream>>>(qx /*agg*/, Ws[l][4], Ws[l][5], Ws[l][6],
                                                Ws[l][7], hB, N);
    }
  }
  k4_pool<<<G, 128, 0, stream>>>(hB, ipos, gate, W1, b1, W2, b2, (float*)d_out, per_g);
}